// Round 8
// baseline (518.592 us; speedup 1.0000x reference)
//
#include <hip/hip_runtime.h>

#define NN 100000
#define NE 1600000

typedef __attribute__((ext_vector_type(16))) int i32x16;

#define SLICES 8
#define FPS 8
#define SLICE_STRIDE ((size_t)NN * FPS)   // 800000 floats per slice region

// ---- bucketed CSR build ----
// bucket = dst >> 9  (512 nodes per bucket)
#define NBKT 196                 // ceil(100000 / 512)
#define NBLK 128                 // partition blocks
#define EPB  (NE / NBLK)         // 12500 edges per partition block
#define PTH  512                 // threads in partition/bucket kernels

__global__ __launch_bounds__(PTH) void k_pcount(const int* __restrict__ dst,
                                                int* __restrict__ pcount) {
  __shared__ int lcnt[NBKT];
  int t = threadIdx.x, b = blockIdx.x;
  for (int i = t; i < NBKT; i += PTH) lcnt[i] = 0;
  __syncthreads();
  int base = b * EPB;
  for (int i = t; i < EPB; i += PTH)
    atomicAdd(&lcnt[dst[base + i] >> 9], 1);
  __syncthreads();
  for (int i = t; i < NBKT; i += PTH)
    pcount[i * NBLK + b] = lcnt[i];   // bucket-major layout
}

__global__ __launch_bounds__(1024) void k_pscan(int* __restrict__ pcount) {
  __shared__ int sh[1024];
  const int TOT = NBKT * NBLK;
  int t = threadIdx.x;
  int base = t * 25;
  int v[25];
  int s = 0;
  #pragma unroll
  for (int k = 0; k < 25; ++k) {
    v[k] = (base + k < TOT) ? pcount[base + k] : 0;
    s += v[k];
  }
  sh[t] = s;
  __syncthreads();
  for (int off = 1; off < 1024; off <<= 1) {
    int x = (t >= off) ? sh[t - off] : 0;
    __syncthreads();
    sh[t] += x;
    __syncthreads();
  }
  int ex = sh[t] - s;
  #pragma unroll
  for (int k = 0; k < 25; ++k) {
    if (base + k < TOT) pcount[base + k] = ex;
    ex += v[k];
  }
}

__global__ __launch_bounds__(PTH) void k_pscatter(const int* __restrict__ src,
                                                  const int* __restrict__ dst,
                                                  const int* __restrict__ pcount,
                                                  int2* __restrict__ staged) {
  __shared__ int lpos[NBKT];
  int t = threadIdx.x, b = blockIdx.x;
  for (int i = t; i < NBKT; i += PTH) lpos[i] = pcount[i * NBLK + b];
  __syncthreads();
  int base = b * EPB;
  for (int i = t; i < EPB; i += PTH) {
    int s = src[base + i], d = dst[base + i];
    int pos = atomicAdd(&lpos[d >> 9], 1);
    staged[pos] = make_int2(s, d);
  }
}

__global__ __launch_bounds__(PTH) void k_bucket(const int2* __restrict__ staged,
                                                const int* __restrict__ pcount,
                                                int* __restrict__ rowptr,
                                                float* __restrict__ dis,
                                                int* __restrict__ col) {
  __shared__ int lcnt[PTH];
  __shared__ int lscan[PTH];
  __shared__ int lpos[PTH];
  int t = threadIdx.x, bkt = blockIdx.x;
  int sbeg = pcount[bkt * NBLK];
  int send = (bkt == NBKT - 1) ? NE : pcount[(bkt + 1) * NBLK];

  lcnt[t] = 0;
  __syncthreads();
  for (int i = sbeg + t; i < send; i += PTH)
    atomicAdd(&lcnt[staged[i].y & 511], 1);
  __syncthreads();

  int v = lcnt[t];
  lscan[t] = v;
  __syncthreads();
  for (int off = 1; off < PTH; off <<= 1) {
    int x = (t >= off) ? lscan[t - off] : 0;
    __syncthreads();
    lscan[t] += x;
    __syncthreads();
  }
  int gbase = sbeg + lscan[t] - v;
  int node = bkt * 512 + t;
  if (node < NN) {
    rowptr[node] = gbase;
    dis[node] = rsqrtf((float)(v + 1));  // +1 self-loop
  }
  lpos[t] = gbase;
  if (bkt == NBKT - 1 && t == 0) rowptr[NN] = NE;
  __syncthreads();

  for (int i = sbeg + t; i < send; i += PTH) {
    int2 e = staged[i];
    col[atomicAdd(&lpos[e.y & 511], 1)] = e.x;
  }
}

// ---- pass A: ts[slice][node][8] = dis * (h @ W) ----
// LDS-tiled GEMM, 128-row tile; thread (tx,ty) computes rows ty*4.. x
// cols tx*8.. ; tx == slice, so epilogue writes straight into slice-major
// layout (contiguous 32 B per node per slice).
__global__ __launch_bounds__(256) void k_xform(const float* __restrict__ h,
                                               const float* __restrict__ W,
                                               const float* __restrict__ dis,
                                               float* __restrict__ ts) {
  __shared__ float hT[64][132];  // [k][row]
  __shared__ float Wl[64][68];   // [k][col]
  const int tid = threadIdx.x;
  const int R0 = blockIdx.x * 128;

  {
    const float4* W4 = (const float4*)W;
    #pragma unroll
    for (int j = 0; j < 4; ++j) {
      int idx = tid + 256 * j;
      float4 v = W4[idx];
      int k = idx >> 4;
      int c = (idx & 15) * 4;
      Wl[k][c + 0] = v.x; Wl[k][c + 1] = v.y;
      Wl[k][c + 2] = v.z; Wl[k][c + 3] = v.w;
    }
  }
  {
    #pragma unroll
    for (int j = 0; j < 8; ++j) {
      int idx = tid + 256 * j;
      int r = idx >> 4;
      int k = (idx & 15) * 4;
      int rg = R0 + r; if (rg > NN - 1) rg = NN - 1;
      float4 v = *(const float4*)(h + (size_t)rg * 64 + k);
      hT[k + 0][r] = v.x; hT[k + 1][r] = v.y;
      hT[k + 2][r] = v.z; hT[k + 3][r] = v.w;
    }
  }
  __syncthreads();

  const int tx = tid & 7;    // slice / cols tx*8..tx*8+7
  const int ty = tid >> 3;   // rows ty*4..ty*4+3
  float acc[4][8];
  #pragma unroll
  for (int i = 0; i < 4; ++i)
    #pragma unroll
    for (int j = 0; j < 8; ++j) acc[i][j] = 0.f;

  #pragma unroll 4
  for (int k = 0; k < 64; ++k) {
    float4 hv = *(const float4*)&hT[k][ty * 4];
    float4 w0 = *(const float4*)&Wl[k][tx * 8];
    float4 w1 = *(const float4*)&Wl[k][tx * 8 + 4];
    float hh[4] = {hv.x, hv.y, hv.z, hv.w};
    float wc[8] = {w0.x, w0.y, w0.z, w0.w, w1.x, w1.y, w1.z, w1.w};
    #pragma unroll
    for (int i = 0; i < 4; ++i)
      #pragma unroll
      for (int j = 0; j < 8; ++j)
        acc[i][j] = fmaf(hh[i], wc[j], acc[i][j]);
  }

  #pragma unroll
  for (int i = 0; i < 4; ++i) {
    int r = R0 + ty * 4 + i;
    if (r < NN) {
      float dr = dis[r];
      float4 o0 = make_float4(acc[i][0] * dr, acc[i][1] * dr,
                              acc[i][2] * dr, acc[i][3] * dr);
      float4 o1 = make_float4(acc[i][4] * dr, acc[i][5] * dr,
                              acc[i][6] * dr, acc[i][7] * dr);
      float* dp = ts + (size_t)tx * SLICE_STRIDE + (size_t)r * 8;
      *(float4*)dp       = o0;
      *(float4*)(dp + 4) = o1;
    }
  }
}

// ---- pass B: out = [relu]( dis_d * (sum_e ts[s][src_e] + ts[s][d]) + b ) ----
// XCD-resident sliced gather: blockIdx&7 = slice (round-robin XCD mapping);
// slice region = 3.2 MB -> fits one XCD's 4 MiB L2, so gathers are L2 hits.
// Lane = (edge_slot 0..7, feat 0..7); 4 edge-quads in flight; shfl_xor reduce.
__global__ __launch_bounds__(256) void k_agg(
    const float* __restrict__ ts, const int* __restrict__ rowptr,
    const int* __restrict__ col, const float* __restrict__ dis,
    const float* __restrict__ bias, float* __restrict__ out, int relu)
{
  const int tid  = threadIdx.x;
  const int lane = tid & 63;
  const int es   = lane >> 3;     // edge slot
  const int ft   = lane & 7;      // feature within slice
  const int slice = blockIdx.x & 7;
  const int swave = __builtin_amdgcn_readfirstlane(
      (int)((blockIdx.x >> 3) * 4 + (tid >> 6)));
  const int nsw = (gridDim.x >> 3) * 4;       // waves per slice

  const float* tb = ts + (size_t)slice * SLICE_STRIDE;
  const float bv = bias[slice * 8 + ft];
  const bool w0 = (es == 0);

  for (int chunk = swave; chunk < NN / 8; chunk += nsw) {
    const int n0 = chunk * 8;
    i32x16 rp;
    asm volatile("s_load_dwordx16 %0, %1, 0x0\n\ts_waitcnt lgkmcnt(0)"
                 : "=s"(rp) : "s"(rowptr + n0));
    #pragma unroll
    for (int i = 0; i < 8; ++i) {
      const int node = n0 + i;
      const int r0 = rp[i], r1 = rp[i + 1];
      const float dn = dis[node];
      float self = tb[(size_t)node * 8 + ft];
      float acc = w0 ? self : 0.f;

      #pragma unroll 1
      for (int e = r0; e < r1; e += 32) {
        int e0 = e + es, e1 = e0 + 8, e2 = e0 + 16, e3 = e0 + 24;
        int c0 = col[e0], c1 = col[e1], c2 = col[e2], c3 = col[e3];
        bool v0 = e0 < r1, v1 = e1 < r1, v2 = e2 < r1, v3 = e3 < r1;
        float g0 = tb[(size_t)(v0 ? c0 : node) * 8 + ft];
        float g1 = tb[(size_t)(v1 ? c1 : node) * 8 + ft];
        float g2 = tb[(size_t)(v2 ? c2 : node) * 8 + ft];
        float g3 = tb[(size_t)(v3 ? c3 : node) * 8 + ft];
        acc += v0 ? g0 : 0.f;
        acc += v1 ? g1 : 0.f;
        acc += v2 ? g2 : 0.f;
        acc += v3 ? g3 : 0.f;
      }

      acc += __shfl_xor(acc, 8);
      acc += __shfl_xor(acc, 16);
      acc += __shfl_xor(acc, 32);
      if (w0) {
        float o = fmaf(dn, acc, bv);
        if (relu) o = fmaxf(o, 0.0f);
        out[(size_t)node * 64 + slice * 8 + ft] = o;
      }
    }
  }
}

extern "C" void kernel_launch(void* const* d_in, const int* in_sizes, int n_in,
                              void* d_out, int out_size, void* d_ws, size_t ws_size,
                              hipStream_t stream) {
  const float* x  = (const float*)d_in[0];
  const int*   ei = (const int*)d_in[1];
  const float* W1 = (const float*)d_in[2];
  const float* b1 = (const float*)d_in[3];
  const float* W2 = (const float*)d_in[4];
  const float* b2 = (const float*)d_in[5];
  const float* W3 = (const float*)d_in[6];
  const float* b3 = (const float*)d_in[7];
  float* out = (float*)d_out;

  const int* src = ei;        // edge_index[0]
  const int* dst = ei + NE;   // edge_index[1]

  char* ws = (char*)d_ws;
  size_t off = 0;
  auto alloc = [&](size_t bytes) {
    void* p = ws + off;
    off = (off + bytes + 255) & ~(size_t)255;
    return p;
  };
  int*   pcount = (int*)alloc((size_t)NBKT * NBLK * 4);
  int*   rowptr = (int*)alloc((size_t)(NN + 1 + 16) * 4); // +16: s_load overrun pad
  float* dis    = (float*)alloc((size_t)NN * 4);
  int2*  staged = (int2*)alloc((size_t)NE * 8);
  int*   col    = (int*)alloc((size_t)(NE + 64) * 4);     // +64: load overrun pad
  float* tbuf   = (float*)alloc((size_t)NN * 64 * 4);     // sliced [8][NN][8]
  (void)ws_size; (void)in_sizes; (void)n_in; (void)out_size;

  k_pcount  <<<NBLK, PTH, 0, stream>>>(dst, pcount);
  k_pscan   <<<1, 1024, 0, stream>>>(pcount);
  k_pscatter<<<NBLK, PTH, 0, stream>>>(src, dst, pcount, staged);
  k_bucket  <<<NBKT, PTH, 0, stream>>>(staged, pcount, rowptr, dis, col);

  const int XF_BLOCKS  = (NN + 127) / 128;   // 782
  const int AGG_BLOCKS = 8 * 784;            // 8 slices x 784 blocks

  // layer i: ts = dis*(h@Wi) sliced ; h' = relu(dis*(S_sum ts) + bi)
  k_xform<<<XF_BLOCKS, 256, 0, stream>>>(x,   W1, dis, tbuf);
  k_agg  <<<AGG_BLOCKS, 256, 0, stream>>>(tbuf, rowptr, col, dis, b1, out, 1);
  k_xform<<<XF_BLOCKS, 256, 0, stream>>>(out, W2, dis, tbuf);
  k_agg  <<<AGG_BLOCKS, 256, 0, stream>>>(tbuf, rowptr, col, dis, b2, out, 1);
  k_xform<<<XF_BLOCKS, 256, 0, stream>>>(out, W3, dis, tbuf);
  k_agg  <<<AGG_BLOCKS, 256, 0, stream>>>(tbuf, rowptr, col, dis, b3, out, 0);
}

// Round 9
// 276.737 us; speedup vs baseline: 1.8740x; 1.8740x over previous
//
#include <hip/hip_runtime.h>

#define NN 100000
#define NE 1600000

typedef __attribute__((ext_vector_type(16))) int i32x16;

// ---- bucketed CSR build ----
// bucket = dst >> 9  (512 nodes per bucket)
#define NBKT 196                 // ceil(100000 / 512)
#define NBLK 128                 // partition blocks
#define EPB  (NE / NBLK)         // 12500 edges per partition block
#define PTH  512                 // threads in partition/bucket kernels

__global__ __launch_bounds__(PTH) void k_pcount(const int* __restrict__ dst,
                                                int* __restrict__ pcount) {
  __shared__ int lcnt[NBKT];
  int t = threadIdx.x, b = blockIdx.x;
  for (int i = t; i < NBKT; i += PTH) lcnt[i] = 0;
  __syncthreads();
  int base = b * EPB;
  for (int i = t; i < EPB; i += PTH)
    atomicAdd(&lcnt[dst[base + i] >> 9], 1);
  __syncthreads();
  for (int i = t; i < NBKT; i += PTH)
    pcount[i * NBLK + b] = lcnt[i];   // bucket-major layout
}

__global__ __launch_bounds__(1024) void k_pscan(int* __restrict__ pcount) {
  __shared__ int sh[1024];
  const int TOT = NBKT * NBLK;
  int t = threadIdx.x;
  int base = t * 25;
  int v[25];
  int s = 0;
  #pragma unroll
  for (int k = 0; k < 25; ++k) {
    v[k] = (base + k < TOT) ? pcount[base + k] : 0;
    s += v[k];
  }
  sh[t] = s;
  __syncthreads();
  for (int off = 1; off < 1024; off <<= 1) {
    int x = (t >= off) ? sh[t - off] : 0;
    __syncthreads();
    sh[t] += x;
    __syncthreads();
  }
  int ex = sh[t] - s;
  #pragma unroll
  for (int k = 0; k < 25; ++k) {
    if (base + k < TOT) pcount[base + k] = ex;
    ex += v[k];
  }
}

__global__ __launch_bounds__(PTH) void k_pscatter(const int* __restrict__ src,
                                                  const int* __restrict__ dst,
                                                  const int* __restrict__ pcount,
                                                  int2* __restrict__ staged) {
  __shared__ int lpos[NBKT];
  int t = threadIdx.x, b = blockIdx.x;
  for (int i = t; i < NBKT; i += PTH) lpos[i] = pcount[i * NBLK + b];
  __syncthreads();
  int base = b * EPB;
  for (int i = t; i < EPB; i += PTH) {
    int s = src[base + i], d = dst[base + i];
    int pos = atomicAdd(&lpos[d >> 9], 1);
    staged[pos] = make_int2(s, d);
  }
}

__global__ __launch_bounds__(PTH) void k_bucket(const int2* __restrict__ staged,
                                                const int* __restrict__ pcount,
                                                int* __restrict__ rowptr,
                                                float* __restrict__ dis,
                                                int* __restrict__ col) {
  __shared__ int lcnt[PTH];
  __shared__ int lscan[PTH];
  __shared__ int lpos[PTH];
  int t = threadIdx.x, bkt = blockIdx.x;
  int sbeg = pcount[bkt * NBLK];
  int send = (bkt == NBKT - 1) ? NE : pcount[(bkt + 1) * NBLK];

  lcnt[t] = 0;
  __syncthreads();
  for (int i = sbeg + t; i < send; i += PTH)
    atomicAdd(&lcnt[staged[i].y & 511], 1);
  __syncthreads();

  int v = lcnt[t];
  lscan[t] = v;
  __syncthreads();
  for (int off = 1; off < PTH; off <<= 1) {
    int x = (t >= off) ? lscan[t - off] : 0;
    __syncthreads();
    lscan[t] += x;
    __syncthreads();
  }
  int gbase = sbeg + lscan[t] - v;
  int node = bkt * 512 + t;
  if (node < NN) {
    rowptr[node] = gbase;
    dis[node] = rsqrtf((float)(v + 1));  // +1 self-loop
  }
  lpos[t] = gbase;
  if (bkt == NBKT - 1 && t == 0) rowptr[NN] = NE;
  __syncthreads();

  for (int i = sbeg + t; i < send; i += PTH) {
    int2 e = staged[i];
    col[atomicAdd(&lpos[e.y & 511], 1)] = e.x;
  }
}

__device__ __forceinline__ unsigned bf16rne(float x) {
  unsigned u = __float_as_uint(x);
  return (u + 0x7fffu + ((u >> 16) & 1u)) >> 16;   // round-nearest-even
}

// ---- pass A: t' = dis * (h @ W), stored bf16 row-major [NN][64] ----
// LDS-tiled fp32 GEMM, 128-row tile; epilogue packs 8 bf16 per thread (16B).
__global__ __launch_bounds__(256) void k_xform(const float* __restrict__ h,
                                               const float* __restrict__ W,
                                               const float* __restrict__ dis,
                                               unsigned short* __restrict__ ts) {
  __shared__ float hT[64][132];  // [k][row]
  __shared__ float Wl[64][68];   // [k][col]
  const int tid = threadIdx.x;
  const int R0 = blockIdx.x * 128;

  {
    const float4* W4 = (const float4*)W;
    #pragma unroll
    for (int j = 0; j < 4; ++j) {
      int idx = tid + 256 * j;
      float4 v = W4[idx];
      int k = idx >> 4;
      int c = (idx & 15) * 4;
      Wl[k][c + 0] = v.x; Wl[k][c + 1] = v.y;
      Wl[k][c + 2] = v.z; Wl[k][c + 3] = v.w;
    }
  }
  {
    #pragma unroll
    for (int j = 0; j < 8; ++j) {
      int idx = tid + 256 * j;
      int r = idx >> 4;
      int k = (idx & 15) * 4;
      int rg = R0 + r; if (rg > NN - 1) rg = NN - 1;
      float4 v = *(const float4*)(h + (size_t)rg * 64 + k);
      hT[k + 0][r] = v.x; hT[k + 1][r] = v.y;
      hT[k + 2][r] = v.z; hT[k + 3][r] = v.w;
    }
  }
  __syncthreads();

  const int tx = tid & 7;    // cols tx*8..tx*8+7
  const int ty = tid >> 3;   // rows ty*4..ty*4+3
  float acc[4][8];
  #pragma unroll
  for (int i = 0; i < 4; ++i)
    #pragma unroll
    for (int j = 0; j < 8; ++j) acc[i][j] = 0.f;

  #pragma unroll 4
  for (int k = 0; k < 64; ++k) {
    float4 hv = *(const float4*)&hT[k][ty * 4];
    float4 w0 = *(const float4*)&Wl[k][tx * 8];
    float4 w1 = *(const float4*)&Wl[k][tx * 8 + 4];
    float hh[4] = {hv.x, hv.y, hv.z, hv.w};
    float wc[8] = {w0.x, w0.y, w0.z, w0.w, w1.x, w1.y, w1.z, w1.w};
    #pragma unroll
    for (int i = 0; i < 4; ++i)
      #pragma unroll
      for (int j = 0; j < 8; ++j)
        acc[i][j] = fmaf(hh[i], wc[j], acc[i][j]);
  }

  #pragma unroll
  for (int i = 0; i < 4; ++i) {
    int r = R0 + ty * 4 + i;
    if (r < NN) {
      float dr = dis[r];
      uint4 pk;
      pk.x = bf16rne(acc[i][0] * dr) | (bf16rne(acc[i][1] * dr) << 16);
      pk.y = bf16rne(acc[i][2] * dr) | (bf16rne(acc[i][3] * dr) << 16);
      pk.z = bf16rne(acc[i][4] * dr) | (bf16rne(acc[i][5] * dr) << 16);
      pk.w = bf16rne(acc[i][6] * dr) | (bf16rne(acc[i][7] * dr) << 16);
      *(uint4*)(ts + (size_t)r * 64 + tx * 8) = pk;
    }
  }
}

// ---- pass B: out = [relu]( dis_d * (sum_e t'[src_e] + t'[d]) + b ) ----
// Round-7 structure; t' rows are bf16 (128 B) -> half the random fetch.
// Wave owns 8 contiguous nodes; rowptr via one s_load_dwordx16; 32 col
// indices per chunk via two s_load_dwordx16; 32 ushort gathers in flight.
__global__ __launch_bounds__(256) void k_agg(
    const unsigned short* __restrict__ ts, const int* __restrict__ rowptr,
    const int* __restrict__ col, const float* __restrict__ dis,
    const float* __restrict__ bias, float* __restrict__ out, int relu)
{
  const int lane = threadIdx.x & 63;
  const int wid  = __builtin_amdgcn_readfirstlane(
                     (int)((blockIdx.x * blockDim.x + threadIdx.x) >> 6));
  const int n0   = wid * 8;
  if (n0 >= NN) return;
  const float bv = bias[lane];

  i32x16 rp;
  asm volatile("s_load_dwordx16 %0, %1, 0x0\n\ts_waitcnt lgkmcnt(0)"
               : "=s"(rp) : "s"(rowptr + n0));

  #pragma unroll
  for (int i = 0; i < 8; ++i) {
    const int node = n0 + i;
    const int r0 = rp[i], r1 = rp[i + 1];
    const float dn = dis[node];
    float a0 = __uint_as_float(
        (unsigned)ts[(size_t)node * 64 + lane] << 16);   // self
    float a1 = 0.f, a2 = 0.f, a3 = 0.f;

    #pragma unroll 1
    for (int e = r0; e < r1; e += 32) {
      i32x16 eb0, eb1;
      asm volatile("s_load_dwordx16 %0, %2, 0x0\n\t"
                   "s_load_dwordx16 %1, %2, 0x40\n\t"
                   "s_waitcnt lgkmcnt(0)"
                   : "=s"(eb0), "=s"(eb1) : "s"(col + e));
      unsigned short g[32];
      #pragma unroll
      for (int u = 0; u < 16; ++u) {
        int c = (e + u < r1) ? eb0[u] : node;       // scalar cselect
        g[u] = ts[(size_t)c * 64 + lane];
      }
      #pragma unroll
      for (int u = 0; u < 16; ++u) {
        int c = (e + 16 + u < r1) ? eb1[u] : node;
        g[16 + u] = ts[(size_t)c * 64 + lane];
      }
      #pragma unroll
      for (int u = 0; u < 32; u += 4) {
        float f0 = __uint_as_float((unsigned)g[u + 0] << 16);
        float f1 = __uint_as_float((unsigned)g[u + 1] << 16);
        float f2 = __uint_as_float((unsigned)g[u + 2] << 16);
        float f3 = __uint_as_float((unsigned)g[u + 3] << 16);
        a0 += (e + u + 0 < r1) ? f0 : 0.f;
        a1 += (e + u + 1 < r1) ? f1 : 0.f;
        a2 += (e + u + 2 < r1) ? f2 : 0.f;
        a3 += (e + u + 3 < r1) ? f3 : 0.f;
      }
    }

    float o = fmaf(dn, (a0 + a1) + (a2 + a3), bv);
    if (relu) o = fmaxf(o, 0.0f);
    out[(size_t)node * 64 + lane] = o;
  }
}

extern "C" void kernel_launch(void* const* d_in, const int* in_sizes, int n_in,
                              void* d_out, int out_size, void* d_ws, size_t ws_size,
                              hipStream_t stream) {
  const float* x  = (const float*)d_in[0];
  const int*   ei = (const int*)d_in[1];
  const float* W1 = (const float*)d_in[2];
  const float* b1 = (const float*)d_in[3];
  const float* W2 = (const float*)d_in[4];
  const float* b2 = (const float*)d_in[5];
  const float* W3 = (const float*)d_in[6];
  const float* b3 = (const float*)d_in[7];
  float* out = (float*)d_out;

  const int* src = ei;        // edge_index[0]
  const int* dst = ei + NE;   // edge_index[1]

  char* ws = (char*)d_ws;
  size_t off = 0;
  auto alloc = [&](size_t bytes) {
    void* p = ws + off;
    off = (off + bytes + 255) & ~(size_t)255;
    return p;
  };
  int*   pcount = (int*)alloc((size_t)NBKT * NBLK * 4);
  int*   rowptr = (int*)alloc((size_t)(NN + 1 + 16) * 4); // +16: s_load overrun pad
  float* dis    = (float*)alloc((size_t)NN * 4);
  int2*  staged = (int2*)alloc((size_t)NE * 8);
  int*   col    = (int*)alloc((size_t)(NE + 64) * 4);     // +64: s_load overrun pad
  unsigned short* tbuf =
      (unsigned short*)alloc((size_t)NN * 64 * 2);        // bf16 [NN][64]
  (void)ws_size; (void)in_sizes; (void)n_in; (void)out_size;

  k_pcount  <<<NBLK, PTH, 0, stream>>>(dst, pcount);
  k_pscan   <<<1, 1024, 0, stream>>>(pcount);
  k_pscatter<<<NBLK, PTH, 0, stream>>>(src, dst, pcount, staged);
  k_bucket  <<<NBKT, PTH, 0, stream>>>(staged, pcount, rowptr, dis, col);

  const int XF_BLOCKS  = (NN + 127) / 128;   // 782
  const int AGG_BLOCKS = (NN / 8 + 3) / 4;   // 12500 waves, 4 per block

  // layer i: t' = dis*(h@Wi) bf16 ; h' = relu(dis*(S_sum t') + bi)
  k_xform<<<XF_BLOCKS, 256, 0, stream>>>(x,   W1, dis, tbuf);
  k_agg  <<<AGG_BLOCKS, 256, 0, stream>>>(tbuf, rowptr, col, dis, b1, out, 1);
  k_xform<<<XF_BLOCKS, 256, 0, stream>>>(out, W2, dis, tbuf);
  k_agg  <<<AGG_BLOCKS, 256, 0, stream>>>(tbuf, rowptr, col, dis, b2, out, 1);
  k_xform<<<XF_BLOCKS, 256, 0, stream>>>(out, W3, dis, tbuf);
  k_agg  <<<AGG_BLOCKS, 256, 0, stream>>>(tbuf, rowptr, col, dis, b3, out, 0);
}

// Round 10
// 276.681 us; speedup vs baseline: 1.8743x; 1.0002x over previous
//
#include <hip/hip_runtime.h>

#define NN 100000
#define NE 1600000

typedef __attribute__((ext_vector_type(16))) int i32x16;

// ---- bucketed CSR build ----
// bucket = dst >> 9  (512 nodes per bucket)
#define NBKT 196                 // ceil(100000 / 512)
#define NBLK 128                 // partition blocks
#define EPB  (NE / NBLK)         // 12500 edges per partition block
#define PTH  512                 // threads in partition/bucket kernels

__global__ __launch_bounds__(PTH) void k_pcount(const int* __restrict__ dst,
                                                int* __restrict__ pcount) {
  __shared__ int lcnt[NBKT];
  int t = threadIdx.x, b = blockIdx.x;
  for (int i = t; i < NBKT; i += PTH) lcnt[i] = 0;
  __syncthreads();
  int base = b * EPB;
  for (int i = t; i < EPB; i += PTH)
    atomicAdd(&lcnt[dst[base + i] >> 9], 1);
  __syncthreads();
  for (int i = t; i < NBKT; i += PTH)
    pcount[i * NBLK + b] = lcnt[i];   // bucket-major layout
}

__global__ __launch_bounds__(1024) void k_pscan(int* __restrict__ pcount) {
  __shared__ int sh[1024];
  const int TOT = NBKT * NBLK;
  int t = threadIdx.x;
  int base = t * 25;
  int v[25];
  int s = 0;
  #pragma unroll
  for (int k = 0; k < 25; ++k) {
    v[k] = (base + k < TOT) ? pcount[base + k] : 0;
    s += v[k];
  }
  sh[t] = s;
  __syncthreads();
  for (int off = 1; off < 1024; off <<= 1) {
    int x = (t >= off) ? sh[t - off] : 0;
    __syncthreads();
    sh[t] += x;
    __syncthreads();
  }
  int ex = sh[t] - s;
  #pragma unroll
  for (int k = 0; k < 25; ++k) {
    if (base + k < TOT) pcount[base + k] = ex;
    ex += v[k];
  }
}

__global__ __launch_bounds__(PTH) void k_pscatter(const int* __restrict__ src,
                                                  const int* __restrict__ dst,
                                                  const int* __restrict__ pcount,
                                                  int2* __restrict__ staged) {
  __shared__ int lpos[NBKT];
  int t = threadIdx.x, b = blockIdx.x;
  for (int i = t; i < NBKT; i += PTH) lpos[i] = pcount[i * NBLK + b];
  __syncthreads();
  int base = b * EPB;
  for (int i = t; i < EPB; i += PTH) {
    int s = src[base + i], d = dst[base + i];
    int pos = atomicAdd(&lpos[d >> 9], 1);
    staged[pos] = make_int2(s, d);
  }
}

__global__ __launch_bounds__(PTH) void k_bucket(const int2* __restrict__ staged,
                                                const int* __restrict__ pcount,
                                                int* __restrict__ rowptr,
                                                float* __restrict__ dis,
                                                int* __restrict__ col) {
  __shared__ int lcnt[PTH];
  __shared__ int lscan[PTH];
  __shared__ int lpos[PTH];
  int t = threadIdx.x, bkt = blockIdx.x;
  int sbeg = pcount[bkt * NBLK];
  int send = (bkt == NBKT - 1) ? NE : pcount[(bkt + 1) * NBLK];

  lcnt[t] = 0;
  __syncthreads();
  for (int i = sbeg + t; i < send; i += PTH)
    atomicAdd(&lcnt[staged[i].y & 511], 1);
  __syncthreads();

  int v = lcnt[t];
  lscan[t] = v;
  __syncthreads();
  for (int off = 1; off < PTH; off <<= 1) {
    int x = (t >= off) ? lscan[t - off] : 0;
    __syncthreads();
    lscan[t] += x;
    __syncthreads();
  }
  int gbase = sbeg + lscan[t] - v;
  int node = bkt * 512 + t;
  if (node < NN) {
    rowptr[node] = gbase;
    dis[node] = rsqrtf((float)(v + 1));  // +1 self-loop
  }
  lpos[t] = gbase;
  if (bkt == NBKT - 1 && t == 0) rowptr[NN] = NE;
  __syncthreads();

  for (int i = sbeg + t; i < send; i += PTH) {
    int2 e = staged[i];
    col[atomicAdd(&lpos[e.y & 511], 1)] = e.x;
  }
}

__device__ __forceinline__ unsigned bf16rne(float x) {
  unsigned u = __float_as_uint(x);
  return (u + 0x7fffu + ((u >> 16) & 1u)) >> 16;   // round-nearest-even
}

// ---- pass A: t' = dis * (h @ W), stored bf16 row-major [NN][64] ----
// LDS-tiled fp32 GEMM, 128-row tile; epilogue packs 8 bf16 per thread (16B).
__global__ __launch_bounds__(256) void k_xform(const float* __restrict__ h,
                                               const float* __restrict__ W,
                                               const float* __restrict__ dis,
                                               unsigned short* __restrict__ ts) {
  __shared__ float hT[64][132];  // [k][row]
  __shared__ float Wl[64][68];   // [k][col]
  const int tid = threadIdx.x;
  const int R0 = blockIdx.x * 128;

  {
    const float4* W4 = (const float4*)W;
    #pragma unroll
    for (int j = 0; j < 4; ++j) {
      int idx = tid + 256 * j;
      float4 v = W4[idx];
      int k = idx >> 4;
      int c = (idx & 15) * 4;
      Wl[k][c + 0] = v.x; Wl[k][c + 1] = v.y;
      Wl[k][c + 2] = v.z; Wl[k][c + 3] = v.w;
    }
  }
  {
    #pragma unroll
    for (int j = 0; j < 8; ++j) {
      int idx = tid + 256 * j;
      int r = idx >> 4;
      int k = (idx & 15) * 4;
      int rg = R0 + r; if (rg > NN - 1) rg = NN - 1;
      float4 v = *(const float4*)(h + (size_t)rg * 64 + k);
      hT[k + 0][r] = v.x; hT[k + 1][r] = v.y;
      hT[k + 2][r] = v.z; hT[k + 3][r] = v.w;
    }
  }
  __syncthreads();

  const int tx = tid & 7;    // cols tx*8..tx*8+7
  const int ty = tid >> 3;   // rows ty*4..ty*4+3
  float acc[4][8];
  #pragma unroll
  for (int i = 0; i < 4; ++i)
    #pragma unroll
    for (int j = 0; j < 8; ++j) acc[i][j] = 0.f;

  #pragma unroll 4
  for (int k = 0; k < 64; ++k) {
    float4 hv = *(const float4*)&hT[k][ty * 4];
    float4 w0 = *(const float4*)&Wl[k][tx * 8];
    float4 w1 = *(const float4*)&Wl[k][tx * 8 + 4];
    float hh[4] = {hv.x, hv.y, hv.z, hv.w};
    float wc[8] = {w0.x, w0.y, w0.z, w0.w, w1.x, w1.y, w1.z, w1.w};
    #pragma unroll
    for (int i = 0; i < 4; ++i)
      #pragma unroll
      for (int j = 0; j < 8; ++j)
        acc[i][j] = fmaf(hh[i], wc[j], acc[i][j]);
  }

  #pragma unroll
  for (int i = 0; i < 4; ++i) {
    int r = R0 + ty * 4 + i;
    if (r < NN) {
      float dr = dis[r];
      uint4 pk;
      pk.x = bf16rne(acc[i][0] * dr) | (bf16rne(acc[i][1] * dr) << 16);
      pk.y = bf16rne(acc[i][2] * dr) | (bf16rne(acc[i][3] * dr) << 16);
      pk.z = bf16rne(acc[i][4] * dr) | (bf16rne(acc[i][5] * dr) << 16);
      pk.w = bf16rne(acc[i][6] * dr) | (bf16rne(acc[i][7] * dr) << 16);
      *(uint4*)(ts + (size_t)r * 64 + tx * 8) = pk;
    }
  }
}

// ---- pass B: out = [relu]( dis_d * (sum_e t'[src_e] + t'[d]) + b ) ----
// Round-7 structure; t' rows are bf16 (128 B) -> half the random fetch.
// Wave owns 8 contiguous nodes; rowptr via one s_load_dwordx16; 32 col
// indices per chunk via two s_load_dwordx16; 32 ushort gathers in flight.
__global__ __launch_bounds__(256) void k_agg(
    const unsigned short* __restrict__ ts, const int* __restrict__ rowptr,
    const int* __restrict__ col, const float* __restrict__ dis,
    const float* __restrict__ bias, float* __restrict__ out, int relu)
{
  const int lane = threadIdx.x & 63;
  const int wid  = __builtin_amdgcn_readfirstlane(
                     (int)((blockIdx.x * blockDim.x + threadIdx.x) >> 6));
  const int n0   = wid * 8;
  if (n0 >= NN) return;
  const float bv = bias[lane];

  i32x16 rp;
  asm volatile("s_load_dwordx16 %0, %1, 0x0\n\ts_waitcnt lgkmcnt(0)"
               : "=s"(rp) : "s"(rowptr + n0));

  #pragma unroll
  for (int i = 0; i < 8; ++i) {
    const int node = n0 + i;
    const int r0 = rp[i], r1 = rp[i + 1];
    const float dn = dis[node];
    float a0 = __uint_as_float(
        (unsigned)ts[(size_t)node * 64 + lane] << 16);   // self
    float a1 = 0.f, a2 = 0.f, a3 = 0.f;

    #pragma unroll 1
    for (int e = r0; e < r1; e += 32) {
      i32x16 eb0, eb1;
      asm volatile("s_load_dwordx16 %0, %2, 0x0\n\t"
                   "s_load_dwordx16 %1, %2, 0x40\n\t"
                   "s_waitcnt lgkmcnt(0)"
                   : "=s"(eb0), "=s"(eb1) : "s"(col + e));
      unsigned short g[32];
      #pragma unroll
      for (int u = 0; u < 16; ++u) {
        int c = (e + u < r1) ? eb0[u] : node;       // scalar cselect
        g[u] = ts[(size_t)c * 64 + lane];
      }
      #pragma unroll
      for (int u = 0; u < 16; ++u) {
        int c = (e + 16 + u < r1) ? eb1[u] : node;
        g[16 + u] = ts[(size_t)c * 64 + lane];
      }
      #pragma unroll
      for (int u = 0; u < 32; u += 4) {
        float f0 = __uint_as_float((unsigned)g[u + 0] << 16);
        float f1 = __uint_as_float((unsigned)g[u + 1] << 16);
        float f2 = __uint_as_float((unsigned)g[u + 2] << 16);
        float f3 = __uint_as_float((unsigned)g[u + 3] << 16);
        a0 += (e + u + 0 < r1) ? f0 : 0.f;
        a1 += (e + u + 1 < r1) ? f1 : 0.f;
        a2 += (e + u + 2 < r1) ? f2 : 0.f;
        a3 += (e + u + 3 < r1) ? f3 : 0.f;
      }
    }

    float o = fmaf(dn, (a0 + a1) + (a2 + a3), bv);
    if (relu) o = fmaxf(o, 0.0f);
    out[(size_t)node * 64 + lane] = o;
  }
}

extern "C" void kernel_launch(void* const* d_in, const int* in_sizes, int n_in,
                              void* d_out, int out_size, void* d_ws, size_t ws_size,
                              hipStream_t stream) {
  const float* x  = (const float*)d_in[0];
  const int*   ei = (const int*)d_in[1];
  const float* W1 = (const float*)d_in[2];
  const float* b1 = (const float*)d_in[3];
  const float* W2 = (const float*)d_in[4];
  const float* b2 = (const float*)d_in[5];
  const float* W3 = (const float*)d_in[6];
  const float* b3 = (const float*)d_in[7];
  float* out = (float*)d_out;

  const int* src = ei;        // edge_index[0]
  const int* dst = ei + NE;   // edge_index[1]

  char* ws = (char*)d_ws;
  size_t off = 0;
  auto alloc = [&](size_t bytes) {
    void* p = ws + off;
    off = (off + bytes + 255) & ~(size_t)255;
    return p;
  };
  int*   pcount = (int*)alloc((size_t)NBKT * NBLK * 4);
  int*   rowptr = (int*)alloc((size_t)(NN + 1 + 16) * 4); // +16: s_load overrun pad
  float* dis    = (float*)alloc((size_t)NN * 4);
  int2*  staged = (int2*)alloc((size_t)NE * 8);
  int*   col    = (int*)alloc((size_t)(NE + 64) * 4);     // +64: s_load overrun pad
  unsigned short* tbuf =
      (unsigned short*)alloc((size_t)NN * 64 * 2);        // bf16 [NN][64]
  (void)ws_size; (void)in_sizes; (void)n_in; (void)out_size;

  k_pcount  <<<NBLK, PTH, 0, stream>>>(dst, pcount);
  k_pscan   <<<1, 1024, 0, stream>>>(pcount);
  k_pscatter<<<NBLK, PTH, 0, stream>>>(src, dst, pcount, staged);
  k_bucket  <<<NBKT, PTH, 0, stream>>>(staged, pcount, rowptr, dis, col);

  const int XF_BLOCKS  = (NN + 127) / 128;   // 782
  const int AGG_BLOCKS = (NN / 8 + 3) / 4;   // 12500 waves, 4 per block

  // layer i: t' = dis*(h@Wi) bf16 ; h' = relu(dis*(S_sum t') + bi)
  k_xform<<<XF_BLOCKS, 256, 0, stream>>>(x,   W1, dis, tbuf);
  k_agg  <<<AGG_BLOCKS, 256, 0, stream>>>(tbuf, rowptr, col, dis, b1, out, 1);
  k_xform<<<XF_BLOCKS, 256, 0, stream>>>(out, W2, dis, tbuf);
  k_agg  <<<AGG_BLOCKS, 256, 0, stream>>>(tbuf, rowptr, col, dis, b2, out, 1);
  k_xform<<<XF_BLOCKS, 256, 0, stream>>>(out, W3, dis, tbuf);
  k_agg  <<<AGG_BLOCKS, 256, 0, stream>>>(tbuf, rowptr, col, dis, b3, out, 0);
}

// Round 11
// 275.642 us; speedup vs baseline: 1.8814x; 1.0038x over previous
//
#include <hip/hip_runtime.h>

#define NN 100000
#define NE 1600000

typedef __attribute__((ext_vector_type(16))) int i32x16;

// ---- bucketed CSR build ----
// bucket = dst >> 9  (512 nodes per bucket)
#define NBKT 196                 // ceil(100000 / 512)
#define NBLK 128                 // partition blocks
#define EPB  (NE / NBLK)         // 12500 edges per partition block
#define PTH  512                 // threads in partition/bucket kernels

__global__ __launch_bounds__(PTH) void k_pcount(const int* __restrict__ dst,
                                                int* __restrict__ pcount) {
  __shared__ int lcnt[NBKT];
  int t = threadIdx.x, b = blockIdx.x;
  for (int i = t; i < NBKT; i += PTH) lcnt[i] = 0;
  __syncthreads();
  int base = b * EPB;
  for (int i = t; i < EPB; i += PTH)
    atomicAdd(&lcnt[dst[base + i] >> 9], 1);
  __syncthreads();
  for (int i = t; i < NBKT; i += PTH)
    pcount[i * NBLK + b] = lcnt[i];   // bucket-major layout
}

__global__ __launch_bounds__(1024) void k_pscan(int* __restrict__ pcount) {
  __shared__ int sh[1024];
  const int TOT = NBKT * NBLK;
  int t = threadIdx.x;
  int base = t * 25;
  int v[25];
  int s = 0;
  #pragma unroll
  for (int k = 0; k < 25; ++k) {
    v[k] = (base + k < TOT) ? pcount[base + k] : 0;
    s += v[k];
  }
  sh[t] = s;
  __syncthreads();
  for (int off = 1; off < 1024; off <<= 1) {
    int x = (t >= off) ? sh[t - off] : 0;
    __syncthreads();
    sh[t] += x;
    __syncthreads();
  }
  int ex = sh[t] - s;
  #pragma unroll
  for (int k = 0; k < 25; ++k) {
    if (base + k < TOT) pcount[base + k] = ex;
    ex += v[k];
  }
}

__global__ __launch_bounds__(PTH) void k_pscatter(const int* __restrict__ src,
                                                  const int* __restrict__ dst,
                                                  const int* __restrict__ pcount,
                                                  int2* __restrict__ staged) {
  __shared__ int lpos[NBKT];
  int t = threadIdx.x, b = blockIdx.x;
  for (int i = t; i < NBKT; i += PTH) lpos[i] = pcount[i * NBLK + b];
  __syncthreads();
  int base = b * EPB;
  for (int i = t; i < EPB; i += PTH) {
    int s = src[base + i], d = dst[base + i];
    int pos = atomicAdd(&lpos[d >> 9], 1);
    staged[pos] = make_int2(s, d);
  }
}

__global__ __launch_bounds__(PTH) void k_bucket(const int2* __restrict__ staged,
                                                const int* __restrict__ pcount,
                                                int* __restrict__ rowptr,
                                                float* __restrict__ dis,
                                                int* __restrict__ col) {
  __shared__ int lcnt[PTH];
  __shared__ int lscan[PTH];
  __shared__ int lpos[PTH];
  int t = threadIdx.x, bkt = blockIdx.x;
  int sbeg = pcount[bkt * NBLK];
  int send = (bkt == NBKT - 1) ? NE : pcount[(bkt + 1) * NBLK];

  lcnt[t] = 0;
  __syncthreads();
  for (int i = sbeg + t; i < send; i += PTH)
    atomicAdd(&lcnt[staged[i].y & 511], 1);
  __syncthreads();

  int v = lcnt[t];
  lscan[t] = v;
  __syncthreads();
  for (int off = 1; off < PTH; off <<= 1) {
    int x = (t >= off) ? lscan[t - off] : 0;
    __syncthreads();
    lscan[t] += x;
    __syncthreads();
  }
  int gbase = sbeg + lscan[t] - v;
  int node = bkt * 512 + t;
  if (node < NN) {
    rowptr[node] = gbase;
    dis[node] = rsqrtf((float)(v + 1));  // +1 self-loop
  }
  lpos[t] = gbase;
  if (bkt == NBKT - 1 && t == 0) rowptr[NN] = NE;
  __syncthreads();

  for (int i = sbeg + t; i < send; i += PTH) {
    int2 e = staged[i];
    col[atomicAdd(&lpos[e.y & 511], 1)] = e.x;
  }
}

__device__ __forceinline__ unsigned bf16rne(float x) {
  unsigned u = __float_as_uint(x);
  return (u + 0x7fffu + ((u >> 16) & 1u)) >> 16;   // round-nearest-even
}

// ---- pass A: t' = dis * (h @ W), stored bf16 row-major [NN][64] ----
// LDS-tiled fp32 GEMM, 128-row tile; epilogue packs 8 bf16 per thread (16B).
__global__ __launch_bounds__(256) void k_xform(const float* __restrict__ h,
                                               const float* __restrict__ W,
                                               const float* __restrict__ dis,
                                               unsigned short* __restrict__ ts) {
  __shared__ float hT[64][132];  // [k][row]
  __shared__ float Wl[64][68];   // [k][col]
  const int tid = threadIdx.x;
  const int R0 = blockIdx.x * 128;

  {
    const float4* W4 = (const float4*)W;
    #pragma unroll
    for (int j = 0; j < 4; ++j) {
      int idx = tid + 256 * j;
      float4 v = W4[idx];
      int k = idx >> 4;
      int c = (idx & 15) * 4;
      Wl[k][c + 0] = v.x; Wl[k][c + 1] = v.y;
      Wl[k][c + 2] = v.z; Wl[k][c + 3] = v.w;
    }
  }
  {
    #pragma unroll
    for (int j = 0; j < 8; ++j) {
      int idx = tid + 256 * j;
      int r = idx >> 4;
      int k = (idx & 15) * 4;
      int rg = R0 + r; if (rg > NN - 1) rg = NN - 1;
      float4 v = *(const float4*)(h + (size_t)rg * 64 + k);
      hT[k + 0][r] = v.x; hT[k + 1][r] = v.y;
      hT[k + 2][r] = v.z; hT[k + 3][r] = v.w;
    }
  }
  __syncthreads();

  const int tx = tid & 7;    // cols tx*8..tx*8+7
  const int ty = tid >> 3;   // rows ty*4..ty*4+3
  float acc[4][8];
  #pragma unroll
  for (int i = 0; i < 4; ++i)
    #pragma unroll
    for (int j = 0; j < 8; ++j) acc[i][j] = 0.f;

  #pragma unroll 4
  for (int k = 0; k < 64; ++k) {
    float4 hv = *(const float4*)&hT[k][ty * 4];
    float4 w0 = *(const float4*)&Wl[k][tx * 8];
    float4 w1 = *(const float4*)&Wl[k][tx * 8 + 4];
    float hh[4] = {hv.x, hv.y, hv.z, hv.w};
    float wc[8] = {w0.x, w0.y, w0.z, w0.w, w1.x, w1.y, w1.z, w1.w};
    #pragma unroll
    for (int i = 0; i < 4; ++i)
      #pragma unroll
      for (int j = 0; j < 8; ++j)
        acc[i][j] = fmaf(hh[i], wc[j], acc[i][j]);
  }

  #pragma unroll
  for (int i = 0; i < 4; ++i) {
    int r = R0 + ty * 4 + i;
    if (r < NN) {
      float dr = dis[r];
      uint4 pk;
      pk.x = bf16rne(acc[i][0] * dr) | (bf16rne(acc[i][1] * dr) << 16);
      pk.y = bf16rne(acc[i][2] * dr) | (bf16rne(acc[i][3] * dr) << 16);
      pk.z = bf16rne(acc[i][4] * dr) | (bf16rne(acc[i][5] * dr) << 16);
      pk.w = bf16rne(acc[i][6] * dr) | (bf16rne(acc[i][7] * dr) << 16);
      *(uint4*)(ts + (size_t)r * 64 + tx * 8) = pk;
    }
  }
}

// ---- pass B: out = [relu]( dis_d * (sum_e t'[src_e] + t'[d]) + b ) ----
// Round-7 structure; t' rows are bf16 (128 B) -> half the random fetch.
// Wave owns 8 contiguous nodes; rowptr via one s_load_dwordx16; 32 col
// indices per chunk via two s_load_dwordx16; 32 ushort gathers in flight.
__global__ __launch_bounds__(256) void k_agg(
    const unsigned short* __restrict__ ts, const int* __restrict__ rowptr,
    const int* __restrict__ col, const float* __restrict__ dis,
    const float* __restrict__ bias, float* __restrict__ out, int relu)
{
  const int lane = threadIdx.x & 63;
  const int wid  = __builtin_amdgcn_readfirstlane(
                     (int)((blockIdx.x * blockDim.x + threadIdx.x) >> 6));
  const int n0   = wid * 8;
  if (n0 >= NN) return;
  const float bv = bias[lane];

  i32x16 rp;
  asm volatile("s_load_dwordx16 %0, %1, 0x0\n\ts_waitcnt lgkmcnt(0)"
               : "=s"(rp) : "s"(rowptr + n0));

  #pragma unroll
  for (int i = 0; i < 8; ++i) {
    const int node = n0 + i;
    const int r0 = rp[i], r1 = rp[i + 1];
    const float dn = dis[node];
    float a0 = __uint_as_float(
        (unsigned)ts[(size_t)node * 64 + lane] << 16);   // self
    float a1 = 0.f, a2 = 0.f, a3 = 0.f;

    #pragma unroll 1
    for (int e = r0; e < r1; e += 32) {
      i32x16 eb0, eb1;
      asm volatile("s_load_dwordx16 %0, %2, 0x0\n\t"
                   "s_load_dwordx16 %1, %2, 0x40\n\t"
                   "s_waitcnt lgkmcnt(0)"
                   : "=s"(eb0), "=s"(eb1) : "s"(col + e));
      unsigned short g[32];
      #pragma unroll
      for (int u = 0; u < 16; ++u) {
        int c = (e + u < r1) ? eb0[u] : node;       // scalar cselect
        g[u] = ts[(size_t)c * 64 + lane];
      }
      #pragma unroll
      for (int u = 0; u < 16; ++u) {
        int c = (e + 16 + u < r1) ? eb1[u] : node;
        g[16 + u] = ts[(size_t)c * 64 + lane];
      }
      #pragma unroll
      for (int u = 0; u < 32; u += 4) {
        float f0 = __uint_as_float((unsigned)g[u + 0] << 16);
        float f1 = __uint_as_float((unsigned)g[u + 1] << 16);
        float f2 = __uint_as_float((unsigned)g[u + 2] << 16);
        float f3 = __uint_as_float((unsigned)g[u + 3] << 16);
        a0 += (e + u + 0 < r1) ? f0 : 0.f;
        a1 += (e + u + 1 < r1) ? f1 : 0.f;
        a2 += (e + u + 2 < r1) ? f2 : 0.f;
        a3 += (e + u + 3 < r1) ? f3 : 0.f;
      }
    }

    float o = fmaf(dn, (a0 + a1) + (a2 + a3), bv);
    if (relu) o = fmaxf(o, 0.0f);
    out[(size_t)node * 64 + lane] = o;
  }
}

extern "C" void kernel_launch(void* const* d_in, const int* in_sizes, int n_in,
                              void* d_out, int out_size, void* d_ws, size_t ws_size,
                              hipStream_t stream) {
  const float* x  = (const float*)d_in[0];
  const int*   ei = (const int*)d_in[1];
  const float* W1 = (const float*)d_in[2];
  const float* b1 = (const float*)d_in[3];
  const float* W2 = (const float*)d_in[4];
  const float* b2 = (const float*)d_in[5];
  const float* W3 = (const float*)d_in[6];
  const float* b3 = (const float*)d_in[7];
  float* out = (float*)d_out;

  const int* src = ei;        // edge_index[0]
  const int* dst = ei + NE;   // edge_index[1]

  char* ws = (char*)d_ws;
  size_t off = 0;
  auto alloc = [&](size_t bytes) {
    void* p = ws + off;
    off = (off + bytes + 255) & ~(size_t)255;
    return p;
  };
  int*   pcount = (int*)alloc((size_t)NBKT * NBLK * 4);
  int*   rowptr = (int*)alloc((size_t)(NN + 1 + 16) * 4); // +16: s_load overrun pad
  float* dis    = (float*)alloc((size_t)NN * 4);
  int2*  staged = (int2*)alloc((size_t)NE * 8);
  int*   col    = (int*)alloc((size_t)(NE + 64) * 4);     // +64: s_load overrun pad
  unsigned short* tbuf =
      (unsigned short*)alloc((size_t)NN * 64 * 2);        // bf16 [NN][64]
  (void)ws_size; (void)in_sizes; (void)n_in; (void)out_size;

  k_pcount  <<<NBLK, PTH, 0, stream>>>(dst, pcount);
  k_pscan   <<<1, 1024, 0, stream>>>(pcount);
  k_pscatter<<<NBLK, PTH, 0, stream>>>(src, dst, pcount, staged);
  k_bucket  <<<NBKT, PTH, 0, stream>>>(staged, pcount, rowptr, dis, col);

  const int XF_BLOCKS  = (NN + 127) / 128;   // 782
  const int AGG_BLOCKS = (NN / 8 + 3) / 4;   // 12500 waves, 4 per block

  // layer i: t' = dis*(h@Wi) bf16 ; h' = relu(dis*(S_sum t') + bi)
  k_xform<<<XF_BLOCKS, 256, 0, stream>>>(x,   W1, dis, tbuf);
  k_agg  <<<AGG_BLOCKS, 256, 0, stream>>>(tbuf, rowptr, col, dis, b1, out, 1);
  k_xform<<<XF_BLOCKS, 256, 0, stream>>>(out, W2, dis, tbuf);
  k_agg  <<<AGG_BLOCKS, 256, 0, stream>>>(tbuf, rowptr, col, dis, b2, out, 1);
  k_xform<<<XF_BLOCKS, 256, 0, stream>>>(out, W3, dis, tbuf);
  k_agg  <<<AGG_BLOCKS, 256, 0, stream>>>(tbuf, rowptr, col, dis, b3, out, 0);
}